// Round 21
// baseline (342.760 us; speedup 1.0000x reference)
//
#include <hip/hip_runtime.h>
#include <cmath>

#define BB   2
#define SS   1024
#define DIMM 3072
#define NHH  24
#define HDD  128
#define MM   (BB * SS)

typedef _Float16 f16;
typedef __attribute__((ext_vector_type(8))) _Float16 half8;
typedef __attribute__((ext_vector_type(4))) float floatx4;
typedef unsigned int u32;
typedef const __attribute__((address_space(1))) u32* gp1;
typedef __attribute__((address_space(3))) u32* lp3;

__device__ __forceinline__ void gload_lds16(const void* g, void* l) {
    __builtin_amdgcn_global_load_lds((gp1)g, (lp3)l, 16, 0, 0);
}

// ---------------- fp32 -> fp16 converter ----------------
__global__ __launch_bounds__(256) void cvt_f16_kernel(
    const float* __restrict__ in, f16* __restrict__ outp, int n8)
{
    int i = blockIdx.x * 256 + threadIdx.x;
    if (i >= n8) return;
    const float4* p = (const float4*)(in + (size_t)i * 8);
    float4 a = p[0], b = p[1];
    half8 h = {(f16)a.x, (f16)a.y, (f16)a.z, (f16)a.w,
               (f16)b.x, (f16)b.y, (f16)b.z, (f16)b.w};
    *(half8*)(outp + (size_t)i * 8) = h;
}

// fused Wq|Wk|Wv converter
__global__ __launch_bounds__(256) void cvt3_f16_kernel(
    const float* __restrict__ w0, const float* __restrict__ w1,
    const float* __restrict__ w2, f16* __restrict__ outp, int n8each)
{
    int i = blockIdx.x * 256 + threadIdx.x;
    int sel = i / n8each;
    int j = i - sel * n8each;
    const float* in = sel == 0 ? w0 : (sel == 1 ? w1 : w2);
    const float4* p = (const float4*)(in + (size_t)j * 8);
    float4 a = p[0], b = p[1];
    half8 h = {(f16)a.x, (f16)a.y, (f16)a.z, (f16)a.w,
               (f16)b.x, (f16)b.y, (f16)b.z, (f16)b.w};
    *(half8*)(outp + (size_t)i * 8) = h;
}

// fused x | Wq | Wk | Wv | Wo converter: x -> outx, weights -> outw (contiguous)
__global__ __launch_bounds__(256) void cvt5_f16_kernel(
    const float* __restrict__ x,
    const float* __restrict__ w0, const float* __restrict__ w1,
    const float* __restrict__ w2, const float* __restrict__ w3,
    f16* __restrict__ outx, f16* __restrict__ outw, int n8x, int n8each)
{
    int i = blockIdx.x * 256 + threadIdx.x;
    const float* src;
    f16* op;
    if (i < n8x) {
        src = x + (size_t)i * 8;
        op  = outx + (size_t)i * 8;
    } else {
        int k = i - n8x;
        int sel = k / n8each;
        int j = k - sel * n8each;
        const float* in = sel == 0 ? w0 : (sel == 1 ? w1 : (sel == 2 ? w2 : w3));
        src = in + (size_t)j * 8;
        op  = outw + (size_t)k * 8;
    }
    const float4* p = (const float4*)src;
    float4 a = p[0], b = p[1];
    half8 h = {(f16)a.x, (f16)a.y, (f16)a.z, (f16)a.w,
               (f16)b.x, (f16)b.y, (f16)b.z, (f16)b.w};
    *(half8*)op = h;
}

// out4[i] += P4[i]  (final split-K reduction, float4)
__global__ __launch_bounds__(256) void reduce_add_kernel(
    float* __restrict__ out, const float* __restrict__ P, int n4)
{
    int i = blockIdx.x * 256 + threadIdx.x;
    if (i >= n4) return;
    float4 o = ((const float4*)out)[i];
    float4 p = ((const float4*)P)[i];
    o.x += p.x; o.y += p.y; o.z += p.z; o.w += p.w;
    ((float4*)out)[i] = o;
}

// ======== PURE-f16 GEMM: BK=32, 3-buffer depth-2 pipeline, counted vmcnt ========
// (r14/r17/r19-proven optimum of the 2-phase family: 695 TF, 0 bank conflicts.)
// seq-aware skip: K/V (sel>0) M-blocks fully >= seq_lens[b] exit early.
template<bool QKV>
__global__ __launch_bounds__(256) void gemm_p32(
    const f16* __restrict__ A,
    const f16* __restrict__ W0, const f16* __restrict__ W1, const f16* __restrict__ W2,
    const float* __restrict__ b0, const float* __restrict__ b1, const float* __restrict__ b2,
    f16* __restrict__ D0, f16* __restrict__ D1, f16* __restrict__ D2,
    float* __restrict__ F, const int* __restrict__ seq)
{
    constexpr int K = DIMM;
    constexpr int NSTEP = K / 32;              // 96
    constexpr int TS = 128 * 32;
    __shared__ __align__(16) f16 As[3][TS];
    __shared__ __align__(16) f16 Bs[3][TS];

    const int tid  = threadIdx.x;
    const int lane = tid & 63;
    const int wave = tid >> 6;
    const int wm = wave >> 1, wn = wave & 1;
    const int lr = lane & 15;
    const int lq = lane >> 4;

    const int id  = blockIdx.x;
    const int cpx = (int)gridDim.x >> 3;
    const int swz = (id & 7) * cpx + (id >> 3);
    const int bm = (swz & 15) << 7;
    const int bn = (swz >> 4) << 7;

    const f16* Wh; const float* bias; f16* D = nullptr;
    int nloc = bn;
    if constexpr (QKV) {
        int sel = bn / DIMM;
        nloc = bn - sel * DIMM;
        Wh   = sel == 0 ? W0 : (sel == 1 ? W1 : W2);
        bias = sel == 0 ? b0 : (sel == 1 ? b1 : b2);
        D    = sel == 0 ? D0 : (sel == 1 ? D1 : D2);
        if (sel > 0) {
            const int batch  = bm >> 10;
            const int sstart = bm & 1023;
            if (sstart >= seq[batch]) return;   // uniform block exit, pre-barrier
        }
    } else { Wh = W0; bias = b0; }

    const int r0 = tid >> 2;
    const int g0 = ((tid & 3) ^ ((r0 >> 1) & 3)) << 3;       // f16 elems
    const int r1 = (tid + 256) >> 2;
    const int g1 = ((tid & 3) ^ ((r1 >> 1) & 3)) << 3;
    const f16* a0  = A  + (size_t)(bm   + r0) * K + g0;
    const f16* a1  = A  + (size_t)(bm   + r1) * K + g1;
    const f16* w0p = Wh + (size_t)(nloc + r0) * K + g0;
    const f16* w1p = Wh + (size_t)(nloc + r1) * K + g1;

    auto STAGE = [&](int t, int buf) {
        const int k0 = t * 32;
        gload_lds16(a0  + k0, &As[buf][(size_t)tid * 8]);
        gload_lds16(a1  + k0, &As[buf][(size_t)(tid + 256) * 8]);
        gload_lds16(w0p + k0, &Bs[buf][(size_t)tid * 8]);
        gload_lds16(w1p + k0, &Bs[buf][(size_t)(tid + 256) * 8]);
    };

    floatx4 acc[4][4];
#pragma unroll
    for (int i = 0; i < 4; ++i)
#pragma unroll
        for (int j = 0; j < 4; ++j) acc[i][j] = (floatx4){0.f, 0.f, 0.f, 0.f};

    auto COMPUTE = [&](int buf) {
        const f16* Ab = &As[buf][0];
        const f16* Bb = &Bs[buf][0];
        half8 af[4], bf[4];
#pragma unroll
        for (int i = 0; i < 4; ++i) {
            int ra = wm * 64 + i * 16 + lr;
            int rb = wn * 64 + i * 16 + lr;
            af[i] = *(const half8*)&Ab[ra * 32 + ((lq ^ ((ra >> 1) & 3)) << 3)];
            bf[i] = *(const half8*)&Bb[rb * 32 + ((lq ^ ((rb >> 1) & 3)) << 3)];
        }
#pragma unroll
        for (int mi = 0; mi < 4; ++mi)
#pragma unroll
            for (int ni = 0; ni < 4; ++ni)
                acc[mi][ni] = __builtin_amdgcn_mfma_f32_16x16x32_f16(af[mi], bf[ni], acc[mi][ni], 0, 0, 0);
    };

    STAGE(0, 0);
    STAGE(1, 1);
    asm volatile("s_waitcnt vmcnt(4)" ::: "memory");
    __builtin_amdgcn_s_barrier();

    int cur = 0, stg = 2;
    for (int ks = 0; ks < NSTEP; ++ks) {
        const bool more = (ks + 2 < NSTEP);
        if (more) STAGE(ks + 2, stg);
        COMPUTE(cur);
        if (more) asm volatile("s_waitcnt vmcnt(4)" ::: "memory");
        else      asm volatile("s_waitcnt vmcnt(0)" ::: "memory");
        __builtin_amdgcn_s_barrier();
        cur = (cur == 2) ? 0 : cur + 1;
        stg = (stg == 2) ? 0 : stg + 1;
    }

    const int crow0 = bm + wm * 64 + (lq << 2);
    const int ccol0 = nloc + wn * 64;
#pragma unroll
    for (int ni = 0; ni < 4; ++ni) {
        const int col = ccol0 + ni * 16 + lr;
        const float bv = bias[col];
#pragma unroll
        for (int mi = 0; mi < 4; ++mi) {
            const int row = crow0 + mi * 16;
#pragma unroll
            for (int r2 = 0; r2 < 4; ++r2) {
                if constexpr (QKV)
                    D[(size_t)(row + r2) * DIMM + col] = (f16)(acc[mi][ni][r2] + bv);
                else
                    F[(size_t)(row + r2) * DIMM + col] = acc[mi][ni][r2] + bv;
            }
        }
    }
}

// ======== Wo GEMM, split-K=2 (768 blocks = exactly 3/CU residency) ========
// Identical r14 schedule over half of K (NSTEP=48). half 0 -> out (+bias),
// half 1 -> partial buffer P. reduce_add_kernel then does out += P.
__global__ __launch_bounds__(256) void gemm_wo_sk(
    const f16* __restrict__ A, const f16* __restrict__ W,
    const float* __restrict__ bias, float* __restrict__ out, float* __restrict__ P)
{
    constexpr int K = DIMM;
    constexpr int KH = K / 2;                  // 1536
    constexpr int NSTEP = KH / 32;             // 48
    constexpr int TS = 128 * 32;
    __shared__ __align__(16) f16 As[3][TS];
    __shared__ __align__(16) f16 Bs[3][TS];

    const int tid  = threadIdx.x;
    const int lane = tid & 63;
    const int wave = tid >> 6;
    const int wm = wave >> 1, wn = wave & 1;
    const int lr = lane & 15;
    const int lq = lane >> 4;

    // bijective XCD swizzle over 768 blocks; swz pairs (2t,2t+1) share a tile
    const int id  = blockIdx.x;
    const int cpx = (int)gridDim.x >> 3;       // 96
    const int swz = (id & 7) * cpx + (id >> 3);
    const int tile = swz >> 1;
    const int half = swz & 1;
    const int bm = (tile & 15) << 7;
    const int bn = (tile >> 4) << 7;
    const int kbase = half * KH;

    const int r0 = tid >> 2;
    const int g0 = ((tid & 3) ^ ((r0 >> 1) & 3)) << 3;
    const int r1 = (tid + 256) >> 2;
    const int g1 = ((tid & 3) ^ ((r1 >> 1) & 3)) << 3;
    const f16* a0  = A + (size_t)(bm + r0) * K + kbase + g0;
    const f16* a1  = A + (size_t)(bm + r1) * K + kbase + g1;
    const f16* w0p = W + (size_t)(bn + r0) * K + kbase + g0;
    const f16* w1p = W + (size_t)(bn + r1) * K + kbase + g1;

    auto STAGE = [&](int t, int buf) {
        const int k0 = t * 32;
        gload_lds16(a0  + k0, &As[buf][(size_t)tid * 8]);
        gload_lds16(a1  + k0, &As[buf][(size_t)(tid + 256) * 8]);
        gload_lds16(w0p + k0, &Bs[buf][(size_t)tid * 8]);
        gload_lds16(w1p + k0, &Bs[buf][(size_t)(tid + 256) * 8]);
    };

    floatx4 acc[4][4];
#pragma unroll
    for (int i = 0; i < 4; ++i)
#pragma unroll
        for (int j = 0; j < 4; ++j) acc[i][j] = (floatx4){0.f, 0.f, 0.f, 0.f};

    auto COMPUTE = [&](int buf) {
        const f16* Ab = &As[buf][0];
        const f16* Bb = &Bs[buf][0];
        half8 af[4], bf[4];
#pragma unroll
        for (int i = 0; i < 4; ++i) {
            int ra = wm * 64 + i * 16 + lr;
            int rb = wn * 64 + i * 16 + lr;
            af[i] = *(const half8*)&Ab[ra * 32 + ((lq ^ ((ra >> 1) & 3)) << 3)];
            bf[i] = *(const half8*)&Bb[rb * 32 + ((lq ^ ((rb >> 1) & 3)) << 3)];
        }
#pragma unroll
        for (int mi = 0; mi < 4; ++mi)
#pragma unroll
            for (int ni = 0; ni < 4; ++ni)
                acc[mi][ni] = __builtin_amdgcn_mfma_f32_16x16x32_f16(af[mi], bf[ni], acc[mi][ni], 0, 0, 0);
    };

    STAGE(0, 0);
    STAGE(1, 1);
    asm volatile("s_waitcnt vmcnt(4)" ::: "memory");
    __builtin_amdgcn_s_barrier();

    int cur = 0, stg = 2;
    for (int ks = 0; ks < NSTEP; ++ks) {
        const bool more = (ks + 2 < NSTEP);
        if (more) STAGE(ks + 2, stg);
        COMPUTE(cur);
        if (more) asm volatile("s_waitcnt vmcnt(4)" ::: "memory");
        else      asm volatile("s_waitcnt vmcnt(0)" ::: "memory");
        __builtin_amdgcn_s_barrier();
        cur = (cur == 2) ? 0 : cur + 1;
        stg = (stg == 2) ? 0 : stg + 1;
    }

    const int crow0 = bm + wm * 64 + (lq << 2);
    const int ccol0 = bn + wn * 64;
    float* dst = (half == 0) ? out : P;
#pragma unroll
    for (int ni = 0; ni < 4; ++ni) {
        const int col = ccol0 + ni * 16 + lr;
        const float bv = (half == 0) ? bias[col] : 0.f;
#pragma unroll
        for (int mi = 0; mi < 4; ++mi) {
            const int row = crow0 + mi * 16;
#pragma unroll
            for (int r2 = 0; r2 < 4; ++r2)
                dst[(size_t)(row + r2) * DIMM + col] = acc[mi][ni][r2] + bv;
        }
    }
}

// ============ MIXED GEMM (r4 kernel — fallback when ws is small) ============
template<bool QKV>
__global__ __launch_bounds__(256) void gemm_f16m(
    const f16* __restrict__ A,
    const float* __restrict__ W0, const float* __restrict__ W1, const float* __restrict__ W2,
    const float* __restrict__ b0, const float* __restrict__ b1, const float* __restrict__ b2,
    f16* __restrict__ D0, f16* __restrict__ D1, f16* __restrict__ D2,
    float* __restrict__ F)
{
    constexpr int K = DIMM;
    constexpr int NSTEP = K / 32;
    __shared__ f16 As[128 * 32];
    __shared__ f16 Bs[128 * 32];

    const int tid  = threadIdx.x;
    const int lane = tid & 63;
    const int wave = tid >> 6;
    const int wm = wave >> 1, wn = wave & 1;
    const int lr = lane & 15;
    const int lq = lane >> 4;

    const int id  = blockIdx.x;
    const int cpx = (int)gridDim.x >> 3;
    const int swz = (id & 7) * cpx + (id >> 3);
    const int bm = (swz & 15) << 7;
    const int bn = (swz >> 4) << 7;

    const float* W; const float* bias; f16* D = nullptr;
    int nloc = bn;
    if constexpr (QKV) {
        int sel = bn / DIMM;
        nloc = bn - sel * DIMM;
        W    = sel == 0 ? W0 : (sel == 1 ? W1 : W2);
        bias = sel == 0 ? b0 : (sel == 1 ? b1 : b2);
        D    = sel == 0 ? D0 : (sel == 1 ? D1 : D2);
    } else { W = W0; bias = b0; }

    const int r0 = tid >> 2;
    const int c8 = (tid & 3) << 3;
    const float* bp0 = W + (size_t)(nloc + r0) * K + c8;
    const float* bp1 = W + (size_t)(nloc + r0 + 64) * K + c8;

    const int arow_l = lane >> 2;
    const int acol_l = (lane & 3) << 3;
    const f16* agbase = A + (size_t)bm * K;

    float4 sb00, sb01, sb10, sb11;
    auto LOADB = [&](int k0) {
        sb00 = *(const float4*)(bp0 + k0); sb01 = *(const float4*)(bp0 + k0 + 4);
        sb10 = *(const float4*)(bp1 + k0); sb11 = *(const float4*)(bp1 + k0 + 4);
    };
    auto STOREB = [&]() {
        half8 h0 = {(f16)sb00.x, (f16)sb00.y, (f16)sb00.z, (f16)sb00.w,
                    (f16)sb01.x, (f16)sb01.y, (f16)sb01.z, (f16)sb01.w};
        half8 h1 = {(f16)sb10.x, (f16)sb10.y, (f16)sb10.z, (f16)sb10.w,
                    (f16)sb11.x, (f16)sb11.y, (f16)sb11.z, (f16)sb11.w};
        *(half8*)&Bs[r0 * 32 + c8]        = h0;
        *(half8*)&Bs[(r0 + 64) * 32 + c8] = h1;
    };

    floatx4 acc[4][4];
#pragma unroll
    for (int i = 0; i < 4; ++i)
#pragma unroll
        for (int j = 0; j < 4; ++j) acc[i][j] = (floatx4){0.f, 0.f, 0.f, 0.f};

    LOADB(0);
    for (int ks = 0; ks < NSTEP; ++ks) {
        const int k0 = ks * 32;
        __syncthreads();
#pragma unroll
        for (int i = 0; i < 2; ++i) {
            int rbase = wave * 32 + i * 16;
            gload_lds16(agbase + (size_t)(rbase + arow_l) * K + k0 + acol_l,
                        &As[rbase * 32]);
        }
        STOREB();
        __syncthreads();
        if (ks + 1 < NSTEP) LOADB(k0 + 32);

        half8 af[4], bf[4];
#pragma unroll
        for (int i = 0; i < 4; ++i) {
            af[i] = *(const half8*)&As[(wm * 64 + i * 16 + lr) * 32 + lq * 8];
            bf[i] = *(const half8*)&Bs[(wn * 64 + i * 16 + lr) * 32 + lq * 8];
        }
#pragma unroll
        for (int mi = 0; mi < 4; ++mi)
#pragma unroll
            for (int ni = 0; ni < 4; ++ni)
                acc[mi][ni] = __builtin_amdgcn_mfma_f32_16x16x32_f16(af[mi], bf[ni], acc[mi][ni], 0, 0, 0);
    }

    const int crow0 = bm + wm * 64 + (lq << 2);
    const int ccol0 = nloc + wn * 64;
#pragma unroll
    for (int ni = 0; ni < 4; ++ni) {
        const int col = ccol0 + ni * 16 + lr;
        const float bv = bias[col];
#pragma unroll
        for (int mi = 0; mi < 4; ++mi) {
            const int row = crow0 + mi * 16;
#pragma unroll
            for (int r2 = 0; r2 < 4; ++r2) {
                if constexpr (QKV)
                    D[(size_t)(row + r2) * DIMM + col] = (f16)(acc[mi][ni][r2] + bv);
                else
                    F[(size_t)(row + r2) * DIMM + col] = acc[mi][ni][r2] + bv;
            }
        }
    }
}

// ---------------- RMSNorm (over 3072) + RoPE, f16 in/out ----------------
__global__ __launch_bounds__(192) void rmsnorm_rope_f16(
    f16* __restrict__ q, f16* __restrict__ k,
    const float* __restrict__ gq, const float* __restrict__ gk,
    const float* __restrict__ freqs, const int* __restrict__ seq)
{
    const int row = blockIdx.x;
    const int s = row & (SS - 1);
    if (blockIdx.y == 1 && s >= seq[row >> 10]) return;
    f16* t = (blockIdx.y == 0) ? q : k;
    const float* g = (blockIdx.y == 0) ? gq : gk;
    const int tid = threadIdx.x;
    f16* base = t + (size_t)row * DIMM + tid * 16;

    half8 v0 = *(const half8*)base;
    half8 v1 = *(const half8*)(base + 8);
    float v[16];
#pragma unroll
    for (int j = 0; j < 8; ++j) { v[j] = (float)v0[j]; v[8 + j] = (float)v1[j]; }

    float ssq = 0.f;
#pragma unroll
    for (int j = 0; j < 16; ++j) ssq += v[j] * v[j];
#pragma unroll
    for (int off = 32; off > 0; off >>= 1) ssq += __shfl_down(ssq, off, 64);
    __shared__ float red[3];
    if ((tid & 63) == 0) red[tid >> 6] = ssq;
    __syncthreads();
    float tot = red[0] + red[1] + red[2];
    float sc = rsqrtf(tot * (1.0f / (float)DIMM) + 1e-6f);

    const float* gp = g + tid * 16;
    float y[16];
#pragma unroll
    for (int j = 0; j < 16; ++j) y[j] = v[j] * sc * gp[j];

#pragma unroll
    for (int p = 0; p < 8; ++p) {
        int idx = tid * 16 + 2 * p;
        int f = (idx & 127) >> 1;
        float ang = freqs[s * 64 + f];
        float cc = cosf(ang), sn = sinf(ang);
        float e = y[2 * p], o = y[2 * p + 1];
        y[2 * p]     = e * cc - o * sn;
        y[2 * p + 1] = e * sn + o * cc;
    }
    half8 o0, o1;
#pragma unroll
    for (int j = 0; j < 8; ++j) { o0[j] = (f16)y[j]; o1[j] = (f16)y[8 + j]; }
    *(half8*)base       = o0;
    *(half8*)(base + 8) = o1;
}

// ---------------- Flash attention: f16 MFMA, wave-parallel online softmax ----------------
__global__ __launch_bounds__(256) void flash_attn_f16(
    const f16* __restrict__ Q, const f16* __restrict__ K,
    const f16* __restrict__ V, const int* __restrict__ seq_lens,
    f16* __restrict__ O)
{
    __shared__ __align__(16) f16 QPs[64 * 128];
    __shared__ __align__(16) f16 Ks[64 * 128];
    __shared__ __align__(16) f16 Vt[128 * 64];

    const int tid  = threadIdx.x;
    const int lane = tid & 63;
    const int wave = tid >> 6;
    const int ln = lane & 15;
    const int lq = lane >> 4;
    const int i0 = blockIdx.x * 64;
    const int h  = blockIdx.y;
    const int b  = blockIdx.z;
    const int slen = seq_lens[b];
    const float scale = 0.08838834764831845f;
    const size_t gstride = NHH * HDD;

    const f16* Qg = Q + ((size_t)(b * SS + i0) * NHH + h) * HDD;
#pragma unroll
    for (int rep = 0; rep < 4; ++rep) {
        int u = tid + rep * 256;
        int r = u >> 4, d0 = (u & 15) << 3;
        half8 qv = *(const half8*)(Qg + (size_t)r * gstride + d0);
        *(half8*)(QPs + r * 128 + (d0 ^ ((r & 7) << 3))) = qv;
    }
    __syncthreads();

    half8 qfrag[4];
    {
        int rq = wave * 16 + ln;
#pragma unroll
        for (int ks = 0; ks < 4; ++ks)
            qfrag[ks] = *(const half8*)(QPs + rq * 128 + ((ks * 32 + lq * 8) ^ ((rq & 7) << 3)));
    }

    floatx4 accO[8];
#pragma unroll
    for (int dt = 0; dt < 8; ++dt) accO[dt] = (floatx4){0.f, 0.f, 0.f, 0.f};
    float mrow[4] = {-3.0e38f, -3.0e38f, -3.0e38f, -3.0e38f};
    float lrow[4] = {0.f, 0.f, 0.f, 0.f};

    const int nT = (slen + 63) >> 6;
    for (int t = 0; t < nT; ++t) {
        const int j0g = t * 64;
        __syncthreads();

        const f16* Kg = K + ((size_t)(b * SS + j0g) * NHH + h) * HDD;
#pragma unroll
        for (int rep = 0; rep < 4; ++rep) {
            int u = tid + rep * 256;
            int r = u >> 4, d0 = (u & 15) << 3;
            half8 kv = *(const half8*)(Kg + (size_t)r * gstride + d0);
            *(half8*)(Ks + r * 128 + (d0 ^ ((r & 7) << 3))) = kv;
        }
        const f16* Vg = V + ((size_t)(b * SS + j0g) * NHH + h) * HDD;
        const half8 zero8 = {(f16)0, (f16)0, (f16)0, (f16)0, (f16)0, (f16)0, (f16)0, (f16)0};
#pragma unroll
        for (int rep = 0; rep < 2; ++rep) {
            int u = tid + rep * 256;
            int jp = u & 31, j0 = jp * 2;
            int d0 = (u >> 5) << 3;
            half8 va = *(const half8*)(Vg + (size_t)j0 * gstride + d0);
            half8 vb = *(const half8*)(Vg + (size_t)(j0 + 1) * gstride + d0);
            if (j0g + j0     >= slen) va = zero8;
            if (j0g + j0 + 1 >= slen) vb = zero8;
#pragma unroll
            for (int i = 0; i < 8; ++i) {
                int d = d0 + i;
                union { f16 h[2]; u32 w; } pk;
                pk.h[0] = va[i]; pk.h[1] = vb[i];
                *(u32*)(Vt + d * 64 + (j0 ^ ((d & 7) << 3))) = pk.w;
            }
        }
        __syncthreads();

        floatx4 acc_s[4];
#pragma unroll
        for (int nt = 0; nt < 4; ++nt) {
            acc_s[nt] = (floatx4){0.f, 0.f, 0.f, 0.f};
            int rk = nt * 16 + ln;
#pragma unroll
            for (int ks = 0; ks < 4; ++ks) {
                half8 kf = *(const half8*)(Ks + rk * 128 + ((ks * 32 + lq * 8) ^ ((rk & 7) << 3)));
                acc_s[nt] = __builtin_amdgcn_mfma_f32_16x16x32_f16(qfrag[ks], kf, acc_s[nt], 0, 0, 0);
            }
        }

        float s[4][4];
#pragma unroll
        for (int nt = 0; nt < 4; ++nt) {
            int j = j0g + nt * 16 + ln;
            bool valid = (j < slen);
#pragma unroll
            for (int r = 0; r < 4; ++r)
                s[nt][r] = valid ? acc_s[nt][r] * scale : -3.0e38f;
        }
        float fct[4];
#pragma unroll
        for (int r = 0; r < 4; ++r) {
            float m4 = fmaxf(fmaxf(s[0][r], s[1][r]), fmaxf(s[2][r], s[3][r]));
            m4 = fmaxf(m4, __shfl_xor(m4, 1, 64));
            m4 = fmaxf(m4, __shfl_xor(m4, 2, 64));
            m4 = fmaxf(m4, __shfl_xor(m4, 4, 64));
            m4 = fmaxf(m4, __shfl_xor(m4, 8, 64));
            float mn = fmaxf(mrow[r], m4);
            fct[r] = __expf(mrow[r] - mn);
            mrow[r] = mn;
            float ls = 0.f;
#pragma unroll
            for (int nt = 0; nt < 4; ++nt) {
                float p = __expf(s[nt][r] - mn);
                s[nt][r] = p;
                ls += p;
            }
            ls += __shfl_xor(ls, 1, 64);
            ls += __shfl_xor(ls, 2, 64);
            ls += __shfl_xor(ls, 4, 64);
            ls += __shfl_xor(ls, 8, 64);
            lrow[r] = lrow[r] * fct[r] + ls;
        }

#pragma unroll
        for (int nt = 0; nt < 4; ++nt) {
#pragma unroll
            for (int r = 0; r < 4; ++r) {
                int rw = lq * 4 + r;
                int j = nt * 16 + ln;
                QPs[(wave * 16 + rw) * 128 + (j ^ ((rw & 7) << 3))] = (f16)s[nt][r];
            }
        }

#pragma unroll
        for (int dt = 0; dt < 8; ++dt)
#pragma unroll
            for (int r = 0; r < 4; ++r) accO[dt][r] *= fct[r];

        half8 pfrag[2];
#pragma unroll
        for (int js = 0; js < 2; ++js)
            pfrag[js] = *(const half8*)(QPs + (wave * 16 + ln) * 128 + ((js * 32 + lq * 8) ^ ((ln & 7) << 3)));
#pragma unroll
        for (int dt = 0; dt < 8; ++dt) {
            int d = dt * 16 + ln;
#pragma unroll
            for (int js = 0; js < 2; ++js) {
                half8 vf = *(const half8*)(Vt + d * 64 + ((js * 32 + lq * 8) ^ ((d & 7) << 3)));
                accO[dt] = __builtin_amdgcn_mfma_f32_16x16x32_f16(pfrag[js], vf, accO[dt], 0, 0, 0);
            }
        }
    }

    float linv[4];
#pragma unroll
    for (int r = 0; r < 4; ++r) linv[r] = 1.0f / lrow[r];
    f16* Og = O + ((size_t)(b * SS + i0) * NHH + h) * HDD;
#pragma unroll
    for (int dt = 0; dt < 8; ++dt) {
#pragma unroll
        for (int r = 0; r < 4; ++r) {
            int qr = wave * 16 + lq * 4 + r;
            int d = dt * 16 + ln;
            Og[(size_t)qr * gstride + d] = (f16)(accO[dt][r] * linv[r]);
        }
    }
}

extern "C" void kernel_launch(void* const* d_in, const int* in_sizes, int n_in,
                              void* d_out, int out_size, void* d_ws, size_t ws_size,
                              hipStream_t stream)
{
    const float* x     = (const float*)d_in[0];
    const int*   seq   = (const int*)d_in[1];
    const float* freqs = (const float*)d_in[3];
    const float* Wq    = (const float*)d_in[4];
    const float* bq    = (const float*)d_in[5];
    const float* Wk    = (const float*)d_in[6];
    const float* bk    = (const float*)d_in[7];
    const float* Wv    = (const float*)d_in[8];
    const float* bv    = (const float*)d_in[9];
    const float* Wo    = (const float*)d_in[10];
    const float* bo    = (const float*)d_in[11];
    const float* gq    = (const float*)d_in[12];
    const float* gk    = (const float*)d_in[13];

    float* out = (float*)d_out;
    const size_t MD = (size_t)MM * DIMM;           // 6,291,456
    const size_t WD = (size_t)DIMM * DIMM;         // 9,437,184

    f16* X16 = (f16*)d_ws;          // later reused as O16
    f16* q16 = X16 + MD;
    f16* k16 = X16 + 2 * MD;
    f16* v16 = (f16*)d_out;         // in d_out; final GEMM overwrites after last use

    const int nMD8 = (int)(MD / 8);
    const int nWD8 = (int)(WD / 8);
    const size_t need1 = (3 * MD + 3 * WD) * sizeof(f16);   // 94.4 MB
    const size_t need2 = (3 * MD + 4 * WD) * sizeof(f16);   // 113.2 MB

    if (ws_size >= need2) {
        f16* Wq16 = X16 + 3 * MD;
        f16* Wk16 = Wq16 + WD;
        f16* Wv16 = Wk16 + WD;
        f16* Wo16 = Wv16 + WD;
        float* Pws = (float*)Wq16;  // 25.2 MB partials; Wq16..Wv16 (56.6 MB) free after QKV
        cvt5_f16_kernel<<<(nMD8 + 4 * nWD8 + 255) / 256, 256, 0, stream>>>(
            x, Wq, Wk, Wv, Wo, X16, Wq16, nMD8, nWD8);
        gemm_p32<true><<<(MM / 128) * (3 * DIMM / 128), 256, 0, stream>>>(
            X16, Wq16, Wk16, Wv16, bq, bk, bv, q16, k16, v16, nullptr, seq);
        rmsnorm_rope_f16<<<dim3(MM, 2), 192, 0, stream>>>(q16, k16, gq, gk, freqs, seq);
        flash_attn_f16<<<dim3(SS / 64, NHH, BB), 256, 0, stream>>>(q16, k16, v16, seq, X16);
        gemm_wo_sk<<<2 * (MM / 128) * (DIMM / 128), 256, 0, stream>>>(
            X16, Wo16, bo, out, Pws);
        reduce_add_kernel<<<(int)(MD / 4 / 256), 256, 0, stream>>>(out, Pws, (int)(MD / 4));
    } else if (ws_size >= need1) {
        f16* Wq16 = X16 + 3 * MD;
        f16* Wk16 = Wq16 + WD;
        f16* Wv16 = Wk16 + WD;
        f16* Wo16 = Wq16;           // reuses Wq16 slot after QKV GEMM (stream-ordered)
        cvt_f16_kernel<<<nMD8 / 256, 256, 0, stream>>>(x, X16, nMD8);
        cvt3_f16_kernel<<<3 * nWD8 / 256, 256, 0, stream>>>(Wq, Wk, Wv, Wq16, nWD8);
        gemm_p32<true><<<(MM / 128) * (3 * DIMM / 128), 256, 0, stream>>>(
            X16, Wq16, Wk16, Wv16, bq, bk, bv, q16, k16, v16, nullptr, seq);
        cvt_f16_kernel<<<nWD8 / 256, 256, 0, stream>>>(Wo, Wo16, nWD8);
        rmsnorm_rope_f16<<<dim3(MM, 2), 192, 0, stream>>>(q16, k16, gq, gk, freqs, seq);
        flash_attn_f16<<<dim3(SS / 64, NHH, BB), 256, 0, stream>>>(q16, k16, v16, seq, X16);
        gemm_p32<false><<<(MM / 128) * (DIMM / 128), 256, 0, stream>>>(
            X16, Wo16, nullptr, nullptr, bo, nullptr, nullptr, nullptr, nullptr, nullptr, out, nullptr);
    } else {
        cvt_f16_kernel<<<nMD8 / 256, 256, 0, stream>>>(x, X16, nMD8);
        gemm_f16m<true><<<(MM / 128) * (3 * DIMM / 128), 256, 0, stream>>>(
            X16, Wq, Wk, Wv, bq, bk, bv, q16, k16, v16, nullptr);
        rmsnorm_rope_f16<<<dim3(MM, 2), 192, 0, stream>>>(q16, k16, gq, gk, freqs, seq);
        flash_attn_f16<<<dim3(SS / 64, NHH, BB), 256, 0, stream>>>(q16, k16, v16, seq, X16);
        gemm_f16m<false><<<(MM / 128) * (DIMM / 128), 256, 0, stream>>>(
            X16, Wo, nullptr, nullptr, bo, nullptr, nullptr, nullptr, nullptr, nullptr, out);
    }
}

// Round 22
// 340.704 us; speedup vs baseline: 1.0060x; 1.0060x over previous
//
#include <hip/hip_runtime.h>
#include <cmath>

#define BB   2
#define SS   1024
#define DIMM 3072
#define NHH  24
#define HDD  128
#define MM   (BB * SS)

typedef _Float16 f16;
typedef __attribute__((ext_vector_type(8))) _Float16 half8;
typedef __attribute__((ext_vector_type(4))) float floatx4;
typedef unsigned int u32;
typedef const __attribute__((address_space(1))) u32* gp1;
typedef __attribute__((address_space(3))) u32* lp3;

__device__ __forceinline__ void gload_lds16(const void* g, void* l) {
    __builtin_amdgcn_global_load_lds((gp1)g, (lp3)l, 16, 0, 0);
}

// ---------------- fp32 -> fp16 converter ----------------
__global__ __launch_bounds__(256) void cvt_f16_kernel(
    const float* __restrict__ in, f16* __restrict__ outp, int n8)
{
    int i = blockIdx.x * 256 + threadIdx.x;
    if (i >= n8) return;
    const float4* p = (const float4*)(in + (size_t)i * 8);
    float4 a = p[0], b = p[1];
    half8 h = {(f16)a.x, (f16)a.y, (f16)a.z, (f16)a.w,
               (f16)b.x, (f16)b.y, (f16)b.z, (f16)b.w};
    *(half8*)(outp + (size_t)i * 8) = h;
}

// fused Wq|Wk|Wv converter
__global__ __launch_bounds__(256) void cvt3_f16_kernel(
    const float* __restrict__ w0, const float* __restrict__ w1,
    const float* __restrict__ w2, f16* __restrict__ outp, int n8each)
{
    int i = blockIdx.x * 256 + threadIdx.x;
    int sel = i / n8each;
    int j = i - sel * n8each;
    const float* in = sel == 0 ? w0 : (sel == 1 ? w1 : w2);
    const float4* p = (const float4*)(in + (size_t)j * 8);
    float4 a = p[0], b = p[1];
    half8 h = {(f16)a.x, (f16)a.y, (f16)a.z, (f16)a.w,
               (f16)b.x, (f16)b.y, (f16)b.z, (f16)b.w};
    *(half8*)(outp + (size_t)i * 8) = h;
}

// fused x | Wq | Wk | Wv | Wo converter: x -> outx, weights -> outw (contiguous)
__global__ __launch_bounds__(256) void cvt5_f16_kernel(
    const float* __restrict__ x,
    const float* __restrict__ w0, const float* __restrict__ w1,
    const float* __restrict__ w2, const float* __restrict__ w3,
    f16* __restrict__ outx, f16* __restrict__ outw, int n8x, int n8each)
{
    int i = blockIdx.x * 256 + threadIdx.x;
    const float* src;
    f16* op;
    if (i < n8x) {
        src = x + (size_t)i * 8;
        op  = outx + (size_t)i * 8;
    } else {
        int k = i - n8x;
        int sel = k / n8each;
        int j = k - sel * n8each;
        const float* in = sel == 0 ? w0 : (sel == 1 ? w1 : (sel == 2 ? w2 : w3));
        src = in + (size_t)j * 8;
        op  = outw + (size_t)k * 8;
    }
    const float4* p = (const float4*)src;
    float4 a = p[0], b = p[1];
    half8 h = {(f16)a.x, (f16)a.y, (f16)a.z, (f16)a.w,
               (f16)b.x, (f16)b.y, (f16)b.z, (f16)b.w};
    *(half8*)op = h;
}

// ======== PURE-f16 GEMM: BK=32, 3-buffer depth-2 pipeline, counted vmcnt ========
// (r14/r17/r19-proven optimum of the 2-phase family: 695 TF, 0 bank conflicts.)
// seq-aware skip: K/V (sel>0) M-blocks fully >= seq_lens[b] exit early.
// NEW (r22): T5 s_setprio(1) around the MFMA cluster — the counted-vmcnt loop
// has wave role diversity (STAGE-issuing vs MFMA-computing), so the CU
// scheduler has something to arbitrate (m218b mechanism; null if lockstep).
template<bool QKV>
__global__ __launch_bounds__(256) void gemm_p32(
    const f16* __restrict__ A,
    const f16* __restrict__ W0, const f16* __restrict__ W1, const f16* __restrict__ W2,
    const float* __restrict__ b0, const float* __restrict__ b1, const float* __restrict__ b2,
    f16* __restrict__ D0, f16* __restrict__ D1, f16* __restrict__ D2,
    float* __restrict__ F, const int* __restrict__ seq)
{
    constexpr int K = DIMM;
    constexpr int NSTEP = K / 32;              // 96
    constexpr int TS = 128 * 32;
    __shared__ __align__(16) f16 As[3][TS];
    __shared__ __align__(16) f16 Bs[3][TS];

    const int tid  = threadIdx.x;
    const int lane = tid & 63;
    const int wave = tid >> 6;
    const int wm = wave >> 1, wn = wave & 1;
    const int lr = lane & 15;
    const int lq = lane >> 4;

    // bijective XCD swizzle (grid % 8 == 0: 1152, 384)
    const int id  = blockIdx.x;
    const int cpx = (int)gridDim.x >> 3;
    const int swz = (id & 7) * cpx + (id >> 3);
    const int bm = (swz & 15) << 7;
    const int bn = (swz >> 4) << 7;

    const f16* Wh; const float* bias; f16* D = nullptr;
    int nloc = bn;
    if constexpr (QKV) {
        int sel = bn / DIMM;
        nloc = bn - sel * DIMM;
        Wh   = sel == 0 ? W0 : (sel == 1 ? W1 : W2);
        bias = sel == 0 ? b0 : (sel == 1 ? b1 : b2);
        D    = sel == 0 ? D0 : (sel == 1 ? D1 : D2);
        if (sel > 0) {
            const int batch  = bm >> 10;
            const int sstart = bm & 1023;
            if (sstart >= seq[batch]) return;   // uniform block exit, pre-barrier
        }
    } else { Wh = W0; bias = b0; }

    const int r0 = tid >> 2;
    const int g0 = ((tid & 3) ^ ((r0 >> 1) & 3)) << 3;       // f16 elems
    const int r1 = (tid + 256) >> 2;
    const int g1 = ((tid & 3) ^ ((r1 >> 1) & 3)) << 3;
    const f16* a0  = A  + (size_t)(bm   + r0) * K + g0;
    const f16* a1  = A  + (size_t)(bm   + r1) * K + g1;
    const f16* w0p = Wh + (size_t)(nloc + r0) * K + g0;
    const f16* w1p = Wh + (size_t)(nloc + r1) * K + g1;

    auto STAGE = [&](int t, int buf) {
        const int k0 = t * 32;
        gload_lds16(a0  + k0, &As[buf][(size_t)tid * 8]);
        gload_lds16(a1  + k0, &As[buf][(size_t)(tid + 256) * 8]);
        gload_lds16(w0p + k0, &Bs[buf][(size_t)tid * 8]);
        gload_lds16(w1p + k0, &Bs[buf][(size_t)(tid + 256) * 8]);
    };

    floatx4 acc[4][4];
#pragma unroll
    for (int i = 0; i < 4; ++i)
#pragma unroll
        for (int j = 0; j < 4; ++j) acc[i][j] = (floatx4){0.f, 0.f, 0.f, 0.f};

    auto COMPUTE = [&](int buf) {
        const f16* Ab = &As[buf][0];
        const f16* Bb = &Bs[buf][0];
        half8 af[4], bf[4];
#pragma unroll
        for (int i = 0; i < 4; ++i) {
            int ra = wm * 64 + i * 16 + lr;
            int rb = wn * 64 + i * 16 + lr;
            af[i] = *(const half8*)&Ab[ra * 32 + ((lq ^ ((ra >> 1) & 3)) << 3)];
            bf[i] = *(const half8*)&Bb[rb * 32 + ((lq ^ ((rb >> 1) & 3)) << 3)];
        }
        __builtin_amdgcn_s_setprio(1);
#pragma unroll
        for (int mi = 0; mi < 4; ++mi)
#pragma unroll
            for (int ni = 0; ni < 4; ++ni)
                acc[mi][ni] = __builtin_amdgcn_mfma_f32_16x16x32_f16(af[mi], bf[ni], acc[mi][ni], 0, 0, 0);
        __builtin_amdgcn_s_setprio(0);
    };

    STAGE(0, 0);
    STAGE(1, 1);
    asm volatile("s_waitcnt vmcnt(4)" ::: "memory");
    __builtin_amdgcn_s_barrier();

    int cur = 0, stg = 2;
    for (int ks = 0; ks < NSTEP; ++ks) {
        const bool more = (ks + 2 < NSTEP);
        if (more) STAGE(ks + 2, stg);
        COMPUTE(cur);
        if (more) asm volatile("s_waitcnt vmcnt(4)" ::: "memory");
        else      asm volatile("s_waitcnt vmcnt(0)" ::: "memory");
        __builtin_amdgcn_s_barrier();
        cur = (cur == 2) ? 0 : cur + 1;
        stg = (stg == 2) ? 0 : stg + 1;
    }

    const int crow0 = bm + wm * 64 + (lq << 2);
    const int ccol0 = nloc + wn * 64;
#pragma unroll
    for (int ni = 0; ni < 4; ++ni) {
        const int col = ccol0 + ni * 16 + lr;
        const float bv = bias[col];
#pragma unroll
        for (int mi = 0; mi < 4; ++mi) {
            const int row = crow0 + mi * 16;
#pragma unroll
            for (int r2 = 0; r2 < 4; ++r2) {
                if constexpr (QKV)
                    D[(size_t)(row + r2) * DIMM + col] = (f16)(acc[mi][ni][r2] + bv);
                else
                    F[(size_t)(row + r2) * DIMM + col] = acc[mi][ni][r2] + bv;
            }
        }
    }
}

// ============ MIXED GEMM (r4 kernel — fallback when ws is small) ============
template<bool QKV>
__global__ __launch_bounds__(256) void gemm_f16m(
    const f16* __restrict__ A,
    const float* __restrict__ W0, const float* __restrict__ W1, const float* __restrict__ W2,
    const float* __restrict__ b0, const float* __restrict__ b1, const float* __restrict__ b2,
    f16* __restrict__ D0, f16* __restrict__ D1, f16* __restrict__ D2,
    float* __restrict__ F)
{
    constexpr int K = DIMM;
    constexpr int NSTEP = K / 32;
    __shared__ f16 As[128 * 32];
    __shared__ f16 Bs[128 * 32];

    const int tid  = threadIdx.x;
    const int lane = tid & 63;
    const int wave = tid >> 6;
    const int wm = wave >> 1, wn = wave & 1;
    const int lr = lane & 15;
    const int lq = lane >> 4;

    const int id  = blockIdx.x;
    const int cpx = (int)gridDim.x >> 3;
    const int swz = (id & 7) * cpx + (id >> 3);
    const int bm = (swz & 15) << 7;
    const int bn = (swz >> 4) << 7;

    const float* W; const float* bias; f16* D = nullptr;
    int nloc = bn;
    if constexpr (QKV) {
        int sel = bn / DIMM;
        nloc = bn - sel * DIMM;
        W    = sel == 0 ? W0 : (sel == 1 ? W1 : W2);
        bias = sel == 0 ? b0 : (sel == 1 ? b1 : b2);
        D    = sel == 0 ? D0 : (sel == 1 ? D1 : D2);
    } else { W = W0; bias = b0; }

    const int r0 = tid >> 2;
    const int c8 = (tid & 3) << 3;
    const float* bp0 = W + (size_t)(nloc + r0) * K + c8;
    const float* bp1 = W + (size_t)(nloc + r0 + 64) * K + c8;

    const int arow_l = lane >> 2;
    const int acol_l = (lane & 3) << 3;
    const f16* agbase = A + (size_t)bm * K;

    float4 sb00, sb01, sb10, sb11;
    auto LOADB = [&](int k0) {
        sb00 = *(const float4*)(bp0 + k0); sb01 = *(const float4*)(bp0 + k0 + 4);
        sb10 = *(const float4*)(bp1 + k0); sb11 = *(const float4*)(bp1 + k0 + 4);
    };
    auto STOREB = [&]() {
        half8 h0 = {(f16)sb00.x, (f16)sb00.y, (f16)sb00.z, (f16)sb00.w,
                    (f16)sb01.x, (f16)sb01.y, (f16)sb01.z, (f16)sb01.w};
        half8 h1 = {(f16)sb10.x, (f16)sb10.y, (f16)sb10.z, (f16)sb10.w,
                    (f16)sb11.x, (f16)sb11.y, (f16)sb11.z, (f16)sb11.w};
        *(half8*)&Bs[r0 * 32 + c8]        = h0;
        *(half8*)&Bs[(r0 + 64) * 32 + c8] = h1;
    };

    floatx4 acc[4][4];
#pragma unroll
    for (int i = 0; i < 4; ++i)
#pragma unroll
        for (int j = 0; j < 4; ++j) acc[i][j] = (floatx4){0.f, 0.f, 0.f, 0.f};

    LOADB(0);
    for (int ks = 0; ks < NSTEP; ++ks) {
        const int k0 = ks * 32;
        __syncthreads();
#pragma unroll
        for (int i = 0; i < 2; ++i) {
            int rbase = wave * 32 + i * 16;
            gload_lds16(agbase + (size_t)(rbase + arow_l) * K + k0 + acol_l,
                        &As[rbase * 32]);
        }
        STOREB();
        __syncthreads();
        if (ks + 1 < NSTEP) LOADB(k0 + 32);

        half8 af[4], bf[4];
#pragma unroll
        for (int i = 0; i < 4; ++i) {
            af[i] = *(const half8*)&As[(wm * 64 + i * 16 + lr) * 32 + lq * 8];
            bf[i] = *(const half8*)&Bs[(wn * 64 + i * 16 + lr) * 32 + lq * 8];
        }
#pragma unroll
        for (int mi = 0; mi < 4; ++mi)
#pragma unroll
            for (int ni = 0; ni < 4; ++ni)
                acc[mi][ni] = __builtin_amdgcn_mfma_f32_16x16x32_f16(af[mi], bf[ni], acc[mi][ni], 0, 0, 0);
    }

    const int crow0 = bm + wm * 64 + (lq << 2);
    const int ccol0 = nloc + wn * 64;
#pragma unroll
    for (int ni = 0; ni < 4; ++ni) {
        const int col = ccol0 + ni * 16 + lr;
        const float bv = bias[col];
#pragma unroll
        for (int mi = 0; mi < 4; ++mi) {
            const int row = crow0 + mi * 16;
#pragma unroll
            for (int r2 = 0; r2 < 4; ++r2) {
                if constexpr (QKV)
                    D[(size_t)(row + r2) * DIMM + col] = (f16)(acc[mi][ni][r2] + bv);
                else
                    F[(size_t)(row + r2) * DIMM + col] = acc[mi][ni][r2] + bv;
            }
        }
    }
}

// ---------------- RMSNorm (over 3072) + RoPE, f16 in/out ----------------
__global__ __launch_bounds__(192) void rmsnorm_rope_f16(
    f16* __restrict__ q, f16* __restrict__ k,
    const float* __restrict__ gq, const float* __restrict__ gk,
    const float* __restrict__ freqs, const int* __restrict__ seq)
{
    const int row = blockIdx.x;
    const int s = row & (SS - 1);
    if (blockIdx.y == 1 && s >= seq[row >> 10]) return;
    f16* t = (blockIdx.y == 0) ? q : k;
    const float* g = (blockIdx.y == 0) ? gq : gk;
    const int tid = threadIdx.x;
    f16* base = t + (size_t)row * DIMM + tid * 16;

    half8 v0 = *(const half8*)base;
    half8 v1 = *(const half8*)(base + 8);
    float v[16];
#pragma unroll
    for (int j = 0; j < 8; ++j) { v[j] = (float)v0[j]; v[8 + j] = (float)v1[j]; }

    float ssq = 0.f;
#pragma unroll
    for (int j = 0; j < 16; ++j) ssq += v[j] * v[j];
#pragma unroll
    for (int off = 32; off > 0; off >>= 1) ssq += __shfl_down(ssq, off, 64);
    __shared__ float red[3];
    if ((tid & 63) == 0) red[tid >> 6] = ssq;
    __syncthreads();
    float tot = red[0] + red[1] + red[2];
    float sc = rsqrtf(tot * (1.0f / (float)DIMM) + 1e-6f);

    const float* gp = g + tid * 16;
    float y[16];
#pragma unroll
    for (int j = 0; j < 16; ++j) y[j] = v[j] * sc * gp[j];

#pragma unroll
    for (int p = 0; p < 8; ++p) {
        int idx = tid * 16 + 2 * p;
        int f = (idx & 127) >> 1;
        float ang = freqs[s * 64 + f];
        float cc = cosf(ang), sn = sinf(ang);
        float e = y[2 * p], o = y[2 * p + 1];
        y[2 * p]     = e * cc - o * sn;
        y[2 * p + 1] = e * sn + o * cc;
    }
    half8 o0, o1;
#pragma unroll
    for (int j = 0; j < 8; ++j) { o0[j] = (f16)y[j]; o1[j] = (f16)y[8 + j]; }
    *(half8*)base       = o0;
    *(half8*)(base + 8) = o1;
}

// ---------------- Flash attention: f16 MFMA, wave-parallel online softmax ----------------
__global__ __launch_bounds__(256) void flash_attn_f16(
    const f16* __restrict__ Q, const f16* __restrict__ K,
    const f16* __restrict__ V, const int* __restrict__ seq_lens,
    f16* __restrict__ O)
{
    __shared__ __align__(16) f16 QPs[64 * 128];
    __shared__ __align__(16) f16 Ks[64 * 128];
    __shared__ __align__(16) f16 Vt[128 * 64];

    const int tid  = threadIdx.x;
    const int lane = tid & 63;
    const int wave = tid >> 6;
    const int ln = lane & 15;
    const int lq = lane >> 4;
    const int i0 = blockIdx.x * 64;
    const int h  = blockIdx.y;
    const int b  = blockIdx.z;
    const int slen = seq_lens[b];
    const float scale = 0.08838834764831845f;
    const size_t gstride = NHH * HDD;

    const f16* Qg = Q + ((size_t)(b * SS + i0) * NHH + h) * HDD;
#pragma unroll
    for (int rep = 0; rep < 4; ++rep) {
        int u = tid + rep * 256;
        int r = u >> 4, d0 = (u & 15) << 3;
        half8 qv = *(const half8*)(Qg + (size_t)r * gstride + d0);
        *(half8*)(QPs + r * 128 + (d0 ^ ((r & 7) << 3))) = qv;
    }
    __syncthreads();

    half8 qfrag[4];
    {
        int rq = wave * 16 + ln;
#pragma unroll
        for (int ks = 0; ks < 4; ++ks)
            qfrag[ks] = *(const half8*)(QPs + rq * 128 + ((ks * 32 + lq * 8) ^ ((rq & 7) << 3)));
    }

    floatx4 accO[8];
#pragma unroll
    for (int dt = 0; dt < 8; ++dt) accO[dt] = (floatx4){0.f, 0.f, 0.f, 0.f};
    float mrow[4] = {-3.0e38f, -3.0e38f, -3.0e38f, -3.0e38f};
    float lrow[4] = {0.f, 0.f, 0.f, 0.f};

    const int nT = (slen + 63) >> 6;
    for (int t = 0; t < nT; ++t) {
        const int j0g = t * 64;
        __syncthreads();

        const f16* Kg = K + ((size_t)(b * SS + j0g) * NHH + h) * HDD;
#pragma unroll
        for (int rep = 0; rep < 4; ++rep) {
            int u = tid + rep * 256;
            int r = u >> 4, d0 = (u & 15) << 3;
            half8 kv = *(const half8*)(Kg + (size_t)r * gstride + d0);
            *(half8*)(Ks + r * 128 + (d0 ^ ((r & 7) << 3))) = kv;
        }
        const f16* Vg = V + ((size_t)(b * SS + j0g) * NHH + h) * HDD;
        const half8 zero8 = {(f16)0, (f16)0, (f16)0, (f16)0, (f16)0, (f16)0, (f16)0, (f16)0};
#pragma unroll
        for (int rep = 0; rep < 2; ++rep) {
            int u = tid + rep * 256;
            int jp = u & 31, j0 = jp * 2;
            int d0 = (u >> 5) << 3;
            half8 va = *(const half8*)(Vg + (size_t)j0 * gstride + d0);
            half8 vb = *(const half8*)(Vg + (size_t)(j0 + 1) * gstride + d0);
            if (j0g + j0     >= slen) va = zero8;
            if (j0g + j0 + 1 >= slen) vb = zero8;
#pragma unroll
            for (int i = 0; i < 8; ++i) {
                int d = d0 + i;
                union { f16 h[2]; u32 w; } pk;
                pk.h[0] = va[i]; pk.h[1] = vb[i];
                *(u32*)(Vt + d * 64 + (j0 ^ ((d & 7) << 3))) = pk.w;
            }
        }
        __syncthreads();

        floatx4 acc_s[4];
#pragma unroll
        for (int nt = 0; nt < 4; ++nt) {
            acc_s[nt] = (floatx4){0.f, 0.f, 0.f, 0.f};
            int rk = nt * 16 + ln;
#pragma unroll
            for (int ks = 0; ks < 4; ++ks) {
                half8 kf = *(const half8*)(Ks + rk * 128 + ((ks * 32 + lq * 8) ^ ((rk & 7) << 3)));
                acc_s[nt] = __builtin_amdgcn_mfma_f32_16x16x32_f16(qfrag[ks], kf, acc_s[nt], 0, 0, 0);
            }
        }

        float s[4][4];
#pragma unroll
        for (int nt = 0; nt < 4; ++nt) {
            int j = j0g + nt * 16 + ln;
            bool valid = (j < slen);
#pragma unroll
            for (int r = 0; r < 4; ++r)
                s[nt][r] = valid ? acc_s[nt][r] * scale : -3.0e38f;
        }
        float fct[4];
#pragma unroll
        for (int r = 0; r < 4; ++r) {
            float m4 = fmaxf(fmaxf(s[0][r], s[1][r]), fmaxf(s[2][r], s[3][r]));
            m4 = fmaxf(m4, __shfl_xor(m4, 1, 64));
            m4 = fmaxf(m4, __shfl_xor(m4, 2, 64));
            m4 = fmaxf(m4, __shfl_xor(m4, 4, 64));
            m4 = fmaxf(m4, __shfl_xor(m4, 8, 64));
            float mn = fmaxf(mrow[r], m4);
            fct[r] = __expf(mrow[r] - mn);
            mrow[r] = mn;
            float ls = 0.f;
#pragma unroll
            for (int nt = 0; nt < 4; ++nt) {
                float p = __expf(s[nt][r] - mn);
                s[nt][r] = p;
                ls += p;
            }
            ls += __shfl_xor(ls, 1, 64);
            ls += __shfl_xor(ls, 2, 64);
            ls += __shfl_xor(ls, 4, 64);
            ls += __shfl_xor(ls, 8, 64);
            lrow[r] = lrow[r] * fct[r] + ls;
        }

#pragma unroll
        for (int nt = 0; nt < 4; ++nt) {
#pragma unroll
            for (int r = 0; r < 4; ++r) {
                int rw = lq * 4 + r;
                int j = nt * 16 + ln;
                QPs[(wave * 16 + rw) * 128 + (j ^ ((rw & 7) << 3))] = (f16)s[nt][r];
            }
        }

#pragma unroll
        for (int dt = 0; dt < 8; ++dt)
#pragma unroll
            for (int r = 0; r < 4; ++r) accO[dt][r] *= fct[r];

        half8 pfrag[2];
#pragma unroll
        for (int js = 0; js < 2; ++js)
            pfrag[js] = *(const half8*)(QPs + (wave * 16 + ln) * 128 + ((js * 32 + lq * 8) ^ ((ln & 7) << 3)));
#pragma unroll
        for (int dt = 0; dt < 8; ++dt) {
            int d = dt * 16 + ln;
#pragma unroll
            for (int js = 0; js < 2; ++js) {
                half8 vf = *(const half8*)(Vt + d * 64 + ((js * 32 + lq * 8) ^ ((d & 7) << 3)));
                accO[dt] = __builtin_amdgcn_mfma_f32_16x16x32_f16(pfrag[js], vf, accO[dt], 0, 0, 0);
            }
        }
    }

    float linv[4];
#pragma unroll
    for (int r = 0; r < 4; ++r) linv[r] = 1.0f / lrow[r];
    f16* Og = O + ((size_t)(b * SS + i0) * NHH + h) * HDD;
#pragma unroll
    for (int dt = 0; dt < 8; ++dt) {
#pragma unroll
        for (int r = 0; r < 4; ++r) {
            int qr = wave * 16 + lq * 4 + r;
            int d = dt * 16 + ln;
            Og[(size_t)qr * gstride + d] = (f16)(accO[dt][r] * linv[r]);
        }
    }
}

extern "C" void kernel_launch(void* const* d_in, const int* in_sizes, int n_in,
                              void* d_out, int out_size, void* d_ws, size_t ws_size,
                              hipStream_t stream)
{
    const float* x     = (const float*)d_in[0];
    const int*   seq   = (const int*)d_in[1];
    const float* freqs = (const float*)d_in[3];
    const float* Wq    = (const float*)d_in[4];
    const float* bq    = (const float*)d_in[5];
    const float* Wk    = (const float*)d_in[6];
    const float* bk    = (const float*)d_in[7];
    const float* Wv    = (const float*)d_in[8];
    const float* bv    = (const float*)d_in[9];
    const float* Wo    = (const float*)d_in[10];
    const float* bo    = (const float*)d_in[11];
    const float* gq    = (const float*)d_in[12];
    const float* gk    = (const float*)d_in[13];

    float* out = (float*)d_out;
    const size_t MD = (size_t)MM * DIMM;           // 6,291,456
    const size_t WD = (size_t)DIMM * DIMM;         // 9,437,184

    f16* X16 = (f16*)d_ws;          // later reused as O16
    f16* q16 = X16 + MD;
    f16* k16 = X16 + 2 * MD;
    f16* v16 = (f16*)d_out;         // in d_out; final GEMM overwrites after last use

    const int nMD8 = (int)(MD / 8);
    const int nWD8 = (int)(WD / 8);
    const size_t need1 = (3 * MD + 3 * WD) * sizeof(f16);   // 94.4 MB
    const size_t need2 = (3 * MD + 4 * WD) * sizeof(f16);   // 113.2 MB

    if (ws_size >= need2) {
        f16* Wq16 = X16 + 3 * MD;
        f16* Wk16 = Wq16 + WD;
        f16* Wv16 = Wk16 + WD;
        f16* Wo16 = Wv16 + WD;
        cvt5_f16_kernel<<<(nMD8 + 4 * nWD8 + 255) / 256, 256, 0, stream>>>(
            x, Wq, Wk, Wv, Wo, X16, Wq16, nMD8, nWD8);
        gemm_p32<true><<<(MM / 128) * (3 * DIMM / 128), 256, 0, stream>>>(
            X16, Wq16, Wk16, Wv16, bq, bk, bv, q16, k16, v16, nullptr, seq);
        rmsnorm_rope_f16<<<dim3(MM, 2), 192, 0, stream>>>(q16, k16, gq, gk, freqs, seq);
        flash_attn_f16<<<dim3(SS / 64, NHH, BB), 256, 0, stream>>>(q16, k16, v16, seq, X16);
        gemm_p32<false><<<(MM / 128) * (DIMM / 128), 256, 0, stream>>>(
            X16, Wo16, nullptr, nullptr, bo, nullptr, nullptr, nullptr, nullptr, nullptr, out, nullptr);
    } else if (ws_size >= need1) {
        f16* Wq16 = X16 + 3 * MD;
        f16* Wk16 = Wq16 + WD;
        f16* Wv16 = Wk16 + WD;
        f16* Wo16 = Wq16;           // reuses Wq16 slot after QKV GEMM (stream-ordered)
        cvt_f16_kernel<<<nMD8 / 256, 256, 0, stream>>>(x, X16, nMD8);
        cvt3_f16_kernel<<<3 * nWD8 / 256, 256, 0, stream>>>(Wq, Wk, Wv, Wq16, nWD8);
        gemm_p32<true><<<(MM / 128) * (3 * DIMM / 128), 256, 0, stream>>>(
            X16, Wq16, Wk16, Wv16, bq, bk, bv, q16, k16, v16, nullptr, seq);
        cvt_f16_kernel<<<nWD8 / 256, 256, 0, stream>>>(Wo, Wo16, nWD8);
        rmsnorm_rope_f16<<<dim3(MM, 2), 192, 0, stream>>>(q16, k16, gq, gk, freqs, seq);
        flash_attn_f16<<<dim3(SS / 64, NHH, BB), 256, 0, stream>>>(q16, k16, v16, seq, X16);
        gemm_p32<false><<<(MM / 128) * (DIMM / 128), 256, 0, stream>>>(
            X16, Wo16, nullptr, nullptr, bo, nullptr, nullptr, nullptr, nullptr, nullptr, out, nullptr);
    } else {
        cvt_f16_kernel<<<nMD8 / 256, 256, 0, stream>>>(x, X16, nMD8);
        gemm_f16m<true><<<(MM / 128) * (3 * DIMM / 128), 256, 0, stream>>>(
            X16, Wq, Wk, Wv, bq, bk, bv, q16, k16, v16, nullptr);
        rmsnorm_rope_f16<<<dim3(MM, 2), 192, 0, stream>>>(q16, k16, gq, gk, freqs, seq);
        flash_attn_f16<<<dim3(SS / 64, NHH, BB), 256, 0, stream>>>(q16, k16, v16, seq, X16);
        gemm_f16m<false><<<(MM / 128) * (DIMM / 128), 256, 0, stream>>>(
            X16, Wo, nullptr, nullptr, bo, nullptr, nullptr, nullptr, nullptr, nullptr, out);
    }
}